// Round 1
// baseline (924.691 us; speedup 1.0000x reference)
//
#include <hip/hip_runtime.h>
#include <hip/hip_bf16.h>
#include <math.h>

// Problem constants
#define BN   16
#define NCH  64      // CIN == COUT == 64
#define HH   256
#define WW   256
#define M0_  20
#define M1_  20

// Workspace layout (in floats)
#define TWA_OFF 0
#define TWA_SZ  (256*40)            // [w][l] (cos, -sin) pairs
#define TWB_OFF (TWA_OFF + TWA_SZ)
#define TWB_SZ  (20*256*2)          // [k][h] (cos, -sin)/256 pairs
#define YW_OFF  (TWB_OFF + TWB_SZ)
#define YW_SZ   (1024*256*40)       // [b*64+i][h][l] complex interleaved
#define X_OFF   (YW_OFF + YW_SZ)
#define X_SZ    (1024*800)          // [b*64+i][k*20+l] complex
#define OF_OFF  (X_OFF + X_SZ)
#define OF_SZ   (1024*800)          // [b*64+o][k*20+l] complex (scaled)
#define Z_OFF   (OF_OFF + OF_SZ)
#define Z_SZ    (1024*256*40)       // [b*64+o][h][l] complex interleaved
// total = 22,630,400 floats = 90.5 MB of d_ws

// ---------------- twiddle tables ----------------
__global__ __launch_bounds__(256) void k_init(float* __restrict__ twA, float* __restrict__ twB){
  int t = blockIdx.x*256 + threadIdx.x;
  if (t >= 5120) return;
  const float step = 6.28318530717958647692f / 256.0f;
  {
    // twA: t = w*20 + l  -> pair at twA[2t]
    int w = t / 20, l = t % 20;
    int m = (w*l) & 255;
    float a = step * (float)m;
    twA[2*t]   =  cosf(a);
    twA[2*t+1] = -sinf(a);
  }
  {
    // twB: t = k*256 + h -> pair at twB[2t], forward ortho 1/256 folded in
    int k = t >> 8, h = t & 255;
    int m = (k*h) & 255;
    float a = step * (float)m;
    twB[2*t]   =  cosf(a) * (1.0f/256.0f);
    twB[2*t+1] = -sinf(a) * (1.0f/256.0f);
  }
}

// ---------------- stage A: DFT along w (20 modes) ----------------
__global__ __launch_bounds__(256) void k_dftw(const float* __restrict__ x,
                                              const float* __restrict__ twA,
                                              float* __restrict__ Yw){
  __shared__ float4 tws[2560];   // 40KB: [w][pair-of-l] (c,-s,c,-s)
  for (int r = threadIdx.x; r < 2560; r += 256) tws[r] = ((const float4*)twA)[r];
  __syncthreads();
  int bi = blockIdx.x;           // b*64+i
  int h  = threadIdx.x;
  const float4* row4 = (const float4*)(x + (((size_t)bi*256 + h) * 256));
  float acc[40];
#pragma unroll
  for (int j=0;j<40;j++) acc[j] = 0.f;
  for (int w4 = 0; w4 < 64; ++w4){
    float4 xv = row4[w4];
#pragma unroll
    for (int s=0;s<4;s++){
      float xvs = (s==0)?xv.x:((s==1)?xv.y:((s==2)?xv.z:xv.w));
      const float4* tp = &tws[(w4*4+s)*10];
#pragma unroll
      for (int p=0;p<10;p++){
        float4 tv = tp[p];       // ds_read_b128, wave-uniform -> broadcast
        acc[4*p+0] += xvs*tv.x;
        acc[4*p+1] += xvs*tv.y;
        acc[4*p+2] += xvs*tv.z;
        acc[4*p+3] += xvs*tv.w;
      }
    }
  }
  float4* dst = (float4*)(Yw + (((size_t)bi*256 + h) * 40));
#pragma unroll
  for (int p=0;p<10;p++) dst[p] = make_float4(acc[4*p],acc[4*p+1],acc[4*p+2],acc[4*p+3]);
}

// ---------------- stage B: DFT along h (20 modes), ortho 1/256 in twB ----------------
__global__ __launch_bounds__(512) void k_dfth(const float* __restrict__ Yw,
                                              const float* __restrict__ twB,
                                              float* __restrict__ X){
  __shared__ float4 yws4[2560];  // 40KB: [h][l] complex
  int bi = blockIdx.x;
  const float4* src = (const float4*)(Yw + (size_t)bi*10240);
  for (int r = threadIdx.x; r < 2560; r += 512) yws4[r] = src[r];
  __syncthreads();
  int t = threadIdx.x;
  if (t < 400){
    int k = t / 20, l = t % 20;
    const float2* yw2 = (const float2*)yws4;
    const float2* tb  = ((const float2*)twB) + k*256;
    float are = 0.f, aim = 0.f;
    for (int h=0; h<256; ++h){
      float2 tv = tb[h];              // (cos,-sin)/256
      float2 yv = yw2[h*20 + l];
      are += yv.x*tv.x - yv.y*tv.y;
      aim += yv.x*tv.y + yv.y*tv.x;
    }
    ((float2*)X)[(size_t)bi*400 + t] = make_float2(are, aim);
  }
}

// ---------------- stage C: per-mode channel mix (complex), scale folded ----------------
__global__ __launch_bounds__(256) void k_mix(const float* __restrict__ X,
                                             const float* __restrict__ wre,
                                             const float* __restrict__ wim,
                                             float* __restrict__ OF){
  __shared__ float2 Xs[1024];    // [b*64+i] at this (k,l)
  int bk = blockIdx.x;
  int kl = (bk & 7)*50 + (bk >> 3);   // XCD-major swizzle: same XCD -> contiguous kl
  const float2* X2 = (const float2*)X;
  for (int r = threadIdx.x; r < 1024; r += 256) Xs[r] = X2[(size_t)r*400 + kl];
  __syncthreads();
  int o = threadIdx.x & 63, bg = threadIdx.x >> 6;
  float ar[4] = {0,0,0,0}, ai[4] = {0,0,0,0};
  for (int i=0;i<64;++i){
    size_t widx = (size_t)(i*64 + o)*400 + kl;
    float wr = wre[widx], wi = wim[widx];
#pragma unroll
    for (int j=0;j<4;j++){
      float2 xv = Xs[(bg*4+j)*64 + i];   // wave-uniform -> LDS broadcast
      ar[j] += xv.x*wr - xv.y*wi;
      ai[j] += xv.x*wi + xv.y*wr;
    }
  }
  int l = kl % 20;
  float scale = (l==0 ? 1.0f : 2.0f) * (1.0f/256.0f);  // Hermitian x2 + inverse ortho
  float2* OF2 = (float2*)OF;
#pragma unroll
  for (int j=0;j<4;j++){
    OF2[(size_t)((bg*4+j)*64 + o)*400 + kl] = make_float2(ar[j]*scale, ai[j]*scale);
  }
}

// ---------------- stage D: zero-padded inverse DFT along h ----------------
__global__ __launch_bounds__(256) void k_idfth(const float* __restrict__ OF,
                                               float* __restrict__ Z){
  __shared__ float2 fs[400];     // [k][l]
  int bo = blockIdx.x;           // b*64+o
  const float2* src = ((const float2*)OF) + (size_t)bo*400;
  for (int r = threadIdx.x; r < 400; r += 256) fs[r] = src[r];
  __syncthreads();
  int h = threadIdx.x;
  float s1, c1;
  sincosf((float)h * 0.02454369260617025967f, &s1, &c1);  // 2*pi*h/256
  float zr[20], zi[20];
#pragma unroll
  for (int l=0;l<20;l++){ zr[l]=0.f; zi[l]=0.f; }
  float tr = 1.f, ti = 0.f;      // e^{+i 2pi k h/256}, k=0
  for (int k=0;k<20;++k){
#pragma unroll
    for (int l=0;l<20;l++){
      float2 f = fs[k*20+l];
      zr[l] += f.x*tr - f.y*ti;
      zi[l] += f.x*ti + f.y*tr;
    }
    float nt = tr*c1 - ti*s1;    // rotate by e^{+i 2pi h/256}
    ti = tr*s1 + ti*c1;
    tr = nt;
  }
  float4* dst = (float4*)(Z + (((size_t)bo*256 + h)*40));
#pragma unroll
  for (int p=0;p<10;p++) dst[p] = make_float4(zr[2*p], zi[2*p], zr[2*p+1], zi[2*p+1]);
}

// ---------------- stage E: irfft along w + bypass 1x1 conv + GELU ----------------
__global__ __launch_bounds__(256) void k_out(const float* __restrict__ x,
                                             const float* __restrict__ Z,
                                             const float* __restrict__ cw,
                                             const float* __restrict__ cb,
                                             float* __restrict__ out){
  __shared__ __hip_bfloat16 xs[64*256];  // 32KB: x[b,:,h,:] as bf16
  __shared__ float4 zs4[640];            // 10KB: Z[b,:,h,:] (o*10+p)
  int b = blockIdx.x >> 8, h = blockIdx.x & 255;
  int w = threadIdx.x;
  const float* xb = x + (((size_t)b*64*256 + h) * 256);
#pragma unroll 4
  for (int i=0;i<64;++i) xs[i*256 + w] = __float2bfloat16(xb[(size_t)i*65536 + w]);
  for (int r = threadIdx.x; r < 640; r += 256){
    int o = r / 10, p = r % 10;
    zs4[r] = ((const float4*)(Z + (((size_t)(b*64+o)*256 + h) * 40)))[p];
  }
  __syncthreads();
  // cos/sin(2*pi*l*w/256) for l=0..19 via recurrence
  float c1, s1;
  sincosf((float)w * 0.02454369260617025967f, &s1, &c1);
  float cl[20], sl[20];
  cl[0] = 1.f; sl[0] = 0.f;
#pragma unroll
  for (int l=1;l<20;l++){
    cl[l] = cl[l-1]*c1 - sl[l-1]*s1;
    sl[l] = sl[l-1]*c1 + cl[l-1]*s1;
  }
  for (int oc=0; oc<4; ++oc){
    float acc[16];
#pragma unroll
    for (int j=0;j<16;j++) acc[j] = cb[oc*16+j];       // uniform -> s_load
    for (int i=0;i<64;++i){
      float xv = __bfloat162float(xs[i*256 + w]);
#pragma unroll
      for (int j=0;j<16;j++) acc[j] += cw[(oc*16+j)*64 + i] * xv;  // SGPR weights
    }
#pragma unroll
    for (int j=0;j<16;j++){
      int o = oc*16+j;
      float sp = 0.f;
#pragma unroll
      for (int p=0;p<10;p++){
        float4 zv = zs4[o*10+p];                        // broadcast b128
        int l = 2*p;
        sp += cl[l]*zv.x   - sl[l]*zv.y;
        sp += cl[l+1]*zv.z - sl[l+1]*zv.w;
      }
      float v = acc[j] + sp;
      // tanh-approx GELU (jax default), overflow-safe via exp(-2|u|)
      float u  = v * (0.7978845608028654f + 0.03567740814f * v * v);
      float au = fabsf(u);
      float e  = __expf(-2.f*au);
      float th = (1.f - e) * __builtin_amdgcn_rcpf(1.f + e);
      th = copysignf(th, u);
      out[(((size_t)(b*64+o)*256 + h)*256) + w] = 0.5f*v*(1.f + th);
    }
  }
}

extern "C" void kernel_launch(void* const* d_in, const int* in_sizes, int n_in,
                              void* d_out, int out_size, void* d_ws, size_t ws_size,
                              hipStream_t stream) {
  const float* x   = (const float*)d_in[0];
  const float* wre = (const float*)d_in[1];
  const float* wim = (const float*)d_in[2];
  const float* cw  = (const float*)d_in[3];
  const float* cb  = (const float*)d_in[4];
  float* out = (float*)d_out;
  float* ws  = (float*)d_ws;

  float* twA = ws + TWA_OFF;
  float* twB = ws + TWB_OFF;
  float* Yw  = ws + YW_OFF;
  float* X   = ws + X_OFF;
  float* OF  = ws + OF_OFF;
  float* Z   = ws + Z_OFF;

  k_init <<<20,   256, 0, stream>>>(twA, twB);
  k_dftw <<<1024, 256, 0, stream>>>(x, twA, Yw);
  k_dfth <<<1024, 512, 0, stream>>>(Yw, twB, X);
  k_mix  <<<400,  256, 0, stream>>>(X, wre, wim, OF);
  k_idfth<<<1024, 256, 0, stream>>>(OF, Z);
  k_out  <<<4096, 256, 0, stream>>>(x, Z, cw, cb, out);
}